// Round 1
// baseline (93.874 us; speedup 1.0000x reference)
//
#include <hip/hip_runtime.h>

// VLAD pooling, fully fused, ZERO workspace (the 256 MiB ws poison fill was
// ~43 us/iter of the 79 us total).
// B=16, S=1024, D=512, KC=12, K=10, fp32.
// Grid = B*2 = 32 blocks x 512 thr. Block (b, half) owns clusters
// k0=half*5 .. k0+4 and reads all of feat[b] (2.1 MB). k-split keeps the
// L2-normalize block-local (it is a per-(b,k) row norm), so no cross-block
// combine is needed. XCD-pairing swizzle co-locates both halves of a batch
// on one XCD so the feat re-read x2 hits L2.
// Per-CU: 2.62M FMA ~ 8.5 us VALU floor on 32 CUs; memory ~2.1 MB/CU
// overlapped. Deterministic, no atomics.

#define B_   16
#define S_   1024
#define D_   512
#define KC_  12
#define K_   10
#define KL_  5            // clusters per block
#define NT   512
#define NPAR 4            // s-parities (par = tid>>7, wave-uniform)

__global__ __launch_bounds__(NT) void vlad_fused(
    const float* __restrict__ feat, const float* __restrict__ score,
    const float* __restrict__ cluster, float* __restrict__ out)
{
    // swizzle: x and x+8 (same XCD under %8 round-robin) = the two halves of
    // one batch.  b = (x&7) + 8*(x>>4), half = (x>>3)&1  (bijective on [0,32))
    const int x    = blockIdx.x;
    const int half = (x >> 3) & 1;
    const int b    = (x & 7) | ((x >> 4) << 3);
    const int k0   = half * KL_;

    const int tid  = threadIdx.x;
    const int lane = tid & 63;
    const int wave = tid >> 6;     // 0..7
    const int par  = tid >> 7;     // 0..3, uniform per wave
    const int col  = tid & 127;    // float4 column in D

    __shared__ float  As[S_][8];              // 32 KB: [0..3]+[4] = a[k0..k0+4]
    __shared__ float4 red[NPAR - 1][KL_][128];// 30 KB parity partials
    __shared__ float  wpart[8][KL_];          // per-wave asum partials
    __shared__ float  asumL[KL_];
    __shared__ float  wsumL[2][KL_];          // 2 waves hold par==0

    // ---- phase 1: softmax, 2 pixels per thread; keep local asum in regs ----
    float aw[KL_];
    #pragma unroll
    for (int j = 0; j < KL_; j++) aw[j] = 0.f;

    #pragma unroll
    for (int t = 0; t < 2; t++) {
        const int s = tid + t * NT;
        const float4* sp = (const float4*)(score + (size_t)(b * S_ + s) * KC_);
        const float4 w0 = sp[0], w1 = sp[1], w2 = sp[2];
        float xv[KC_] = {w0.x, w0.y, w0.z, w0.w, w1.x, w1.y, w1.z, w1.w,
                         w2.x, w2.y, w2.z, w2.w};
        float m = xv[0];
        #pragma unroll
        for (int k = 1; k < KC_; k++) m = fmaxf(m, xv[k]);
        float sum = 0.f;
        #pragma unroll
        for (int k = 0; k < KC_; k++) { xv[k] = __expf(xv[k] - m); sum += xv[k]; }
        const float inv = 1.0f / sum;
        const float a0 = xv[k0] * inv, a1 = xv[k0 + 1] * inv,
                    a2 = xv[k0 + 2] * inv, a3 = xv[k0 + 3] * inv,
                    a4 = xv[k0 + 4] * inv;
        *(float4*)&As[s][0] = make_float4(a0, a1, a2, a3);
        As[s][4] = a4;
        aw[0] += a0; aw[1] += a1; aw[2] += a2; aw[3] += a3; aw[4] += a4;
    }
    // wave-reduce the 5 asum values
    #pragma unroll
    for (int j = 0; j < KL_; j++) {
        float r = aw[j];
        #pragma unroll
        for (int off = 32; off > 0; off >>= 1) r += __shfl_down(r, off, 64);
        if (lane == 0) wpart[wave][j] = r;
    }
    __syncthreads();                      // As + wpart visible
    if (tid < KL_) {                      // finalize asum (read after next sync)
        float s = 0.f;
        #pragma unroll
        for (int w = 0; w < 8; w++) s += wpart[w][tid];
        asumL[tid] = s;
    }

    // ---- phase 2: accumulate 256 pixels/thread over 5 clusters ----
    float acc[KL_][4];
    #pragma unroll
    for (int k = 0; k < KL_; k++)
        acc[k][0] = acc[k][1] = acc[k][2] = acc[k][3] = 0.f;

    const float4* fp = (const float4*)(feat + (size_t)b * S_ * D_) + col;
    #pragma unroll 8
    for (int i = 0; i < S_ / NPAR; i++) {
        const int s = (i << 2) | par;
        const float4 v   = fp[(size_t)s * (D_ / 4)];
        const float4 a03 = *(const float4*)&As[s][0];   // uniform broadcast
        const float  a4  = As[s][4];
        acc[0][0] += a03.x * v.x; acc[0][1] += a03.x * v.y;
        acc[0][2] += a03.x * v.z; acc[0][3] += a03.x * v.w;
        acc[1][0] += a03.y * v.x; acc[1][1] += a03.y * v.y;
        acc[1][2] += a03.y * v.z; acc[1][3] += a03.y * v.w;
        acc[2][0] += a03.z * v.x; acc[2][1] += a03.z * v.y;
        acc[2][2] += a03.z * v.z; acc[2][3] += a03.z * v.w;
        acc[3][0] += a03.w * v.x; acc[3][1] += a03.w * v.y;
        acc[3][2] += a03.w * v.z; acc[3][3] += a03.w * v.w;
        acc[4][0] += a4   * v.x; acc[4][1] += a4   * v.y;
        acc[4][2] += a4   * v.z; acc[4][3] += a4   * v.w;
    }

    // ---- phase 3: parity combine via LDS (par 1..3 -> par 0) ----
    if (par) {
        #pragma unroll
        for (int k = 0; k < KL_; k++)
            red[par - 1][k][col] =
                make_float4(acc[k][0], acc[k][1], acc[k][2], acc[k][3]);
    }
    __syncthreads();                      // red + asumL visible

    float r[KL_][4];
    float sq[KL_];
    if (!par) {
        #pragma unroll
        for (int k = 0; k < KL_; k++) {
            float v0 = acc[k][0], v1 = acc[k][1], v2 = acc[k][2], v3 = acc[k][3];
            #pragma unroll
            for (int p = 0; p < NPAR - 1; p++) {
                const float4 t = red[p][k][col];
                v0 += t.x; v1 += t.y; v2 += t.z; v3 += t.w;
            }
            const float  asv = asumL[k];
            const float4 cv  = *(const float4*)(cluster + (size_t)(k0 + k) * D_ + col * 4);
            v0 -= asv * cv.x; v1 -= asv * cv.y; v2 -= asv * cv.z; v3 -= asv * cv.w;
            r[k][0] = v0; r[k][1] = v1; r[k][2] = v2; r[k][3] = v3;
            sq[k] = v0 * v0 + v1 * v1 + v2 * v2 + v3 * v3;
        }
        #pragma unroll
        for (int k = 0; k < KL_; k++) {
            float s = sq[k];
            #pragma unroll
            for (int off = 32; off > 0; off >>= 1) s += __shfl_down(s, off, 64);
            if (lane == 0) wsumL[wave][k] = s;   // waves 0,1
        }
    }
    __syncthreads();

    // ---- phase 4: normalize + store ----
    if (!par) {
        #pragma unroll
        for (int k = 0; k < KL_; k++) {
            const float tot = wsumL[0][k] + wsumL[1][k];
            const float sc  = rsqrtf(fmaxf(tot, 1e-12f));
            *(float4*)(out + (size_t)(b * K_ + k0 + k) * D_ + col * 4) =
                make_float4(r[k][0] * sc, r[k][1] * sc, r[k][2] * sc, r[k][3] * sc);
        }
    }
}

extern "C" void kernel_launch(void* const* d_in, const int* in_sizes, int n_in,
                              void* d_out, int out_size, void* d_ws, size_t ws_size,
                              hipStream_t stream) {
    const float* feat    = (const float*)d_in[0];
    const float* score   = (const float*)d_in[1];
    const float* cluster = (const float*)d_in[2];
    float* out = (float*)d_out;
    (void)d_ws; (void)ws_size;   // workspace intentionally unused

    vlad_fused<<<B_ * 2, NT, 0, stream>>>(feat, score, cluster, out);
}

// Round 2
// 80.622 us; speedup vs baseline: 1.1644x; 1.1644x over previous
//
#include <hip/hip_runtime.h>

// VLAD pooling: B=16, S=1024, D=512, KC=12, K=10, fp32.
// The harness poison-fills the 256 MiB workspace EVERY iteration (~43.5 us,
// unconditional — measured round 1 with ws unused). So ws is free; minimize
// kernel time with full-chip parallelism.
// K1: 256 blocks (b,chunk) x 512 thr. All 16 per-thread feat float4 loads
//     issued UP-FRONT (deep vmcnt pipeline, ~130 VGPR under
//     __launch_bounds__(512,2)) and overlapped with the softmax phase.
//     asum via wave-shuffle in the softmax wave. Parity combine in LDS.
// K2: 160 blocks (b,k) x 256 thr, all 16 chunk float2 loads up-front,
//     subtract asum*cluster, L2-normalize.

#define B_   16
#define S_   1024
#define D_   512
#define KC_  12
#define K_   10
#define CH_  16            // s-chunks per batch
#define SCH_ (S_ / CH_)    // 64 pixels per chunk
#define NT1  512
#define NPAR 4             // s-parities (par = tid>>7, wave-uniform)
#define NPX  (SCH_ / NPAR) // 16 pixels per thread

__global__ __launch_bounds__(NT1, 2) void vlad_accum(
    const float* __restrict__ feat, const float* __restrict__ score,
    float* __restrict__ part, float* __restrict__ asum_part)
{
    const int bid = blockIdx.x;
    const int b = bid / CH_, c = bid % CH_;
    const int s0 = c * SCH_;
    const int tid = threadIdx.x;
    const int par = tid >> 7;     // 0..3, wave-pair-uniform
    const int col = tid & 127;    // float4 column in D

    __shared__ float  As[SCH_][KC_];           // 3 KB softmax weights
    __shared__ float4 red[NPAR - 1][K_][128];  // 60 KB parity partials

    // -- issue score loads (wave 0) then ALL 16 feat loads (deep pipeline) --
    float4 w0, w1, w2;
    if (tid < SCH_) {
        const float4* sp = (const float4*)(score + (size_t)(b * S_ + s0 + tid) * KC_);
        w0 = sp[0]; w1 = sp[1]; w2 = sp[2];
    }

    const float4* fp = (const float4*)(feat + (size_t)(b * S_ + s0) * D_) + col;
    float4 v[NPX];
    #pragma unroll
    for (int i = 0; i < NPX; i++)
        v[i] = fp[(size_t)(NPAR * i + par) * (D_ / 4)];

    // -- softmax + asum wave-reduce, overlapped with feat loads in flight --
    if (tid < SCH_) {
        float x[KC_] = {w0.x, w0.y, w0.z, w0.w, w1.x, w1.y, w1.z, w1.w,
                        w2.x, w2.y, w2.z, w2.w};
        float m = x[0];
        #pragma unroll
        for (int k = 1; k < KC_; k++) m = fmaxf(m, x[k]);
        float sum = 0.f;
        #pragma unroll
        for (int k = 0; k < KC_; k++) { x[k] = __expf(x[k] - m); sum += x[k]; }
        const float inv = 1.0f / sum;
        #pragma unroll
        for (int k = 0; k < KC_; k++) {
            x[k] *= inv;
            As[tid][k] = x[k];
        }
        // wave-reduce the 10 needed asum values (tid<64 == full wave 0)
        #pragma unroll
        for (int k = 0; k < K_; k++) {
            float r = x[k];
            #pragma unroll
            for (int off = 32; off > 0; off >>= 1) r += __shfl_down(r, off, 64);
            if (tid == 0) asum_part[(b * CH_ + c) * K_ + k] = r;
        }
    }
    __syncthreads();

    // -- main accumulate: consume the 16 prefetched float4s --
    float acc[K_][4];
    #pragma unroll
    for (int k = 0; k < K_; k++)
        acc[k][0] = acc[k][1] = acc[k][2] = acc[k][3] = 0.f;

    #pragma unroll
    for (int i = 0; i < NPX; i++) {
        const int s = NPAR * i + par;
        const float4 a0 = *(const float4*)&As[s][0];   // uniform broadcast
        const float4 a1 = *(const float4*)&As[s][4];
        const float2 a2 = *(const float2*)&As[s][8];
        const float a[K_] = {a0.x, a0.y, a0.z, a0.w, a1.x, a1.y, a1.z, a1.w,
                             a2.x, a2.y};
        #pragma unroll
        for (int k = 0; k < K_; k++) {
            acc[k][0] += a[k] * v[i].x;
            acc[k][1] += a[k] * v[i].y;
            acc[k][2] += a[k] * v[i].z;
            acc[k][3] += a[k] * v[i].w;
        }
    }

    // -- parity combine (par 1..3 -> par 0) and store --
    if (par) {
        #pragma unroll
        for (int k = 0; k < K_; k++)
            red[par - 1][k][col] =
                make_float4(acc[k][0], acc[k][1], acc[k][2], acc[k][3]);
    }
    __syncthreads();
    if (!par) {
        float* pp = part + (((size_t)(b * K_) * CH_ + c) * D_) + col * 4;
        #pragma unroll
        for (int k = 0; k < K_; k++) {
            float v0 = acc[k][0], v1 = acc[k][1], v2 = acc[k][2], v3 = acc[k][3];
            #pragma unroll
            for (int p = 0; p < NPAR - 1; p++) {
                const float4 t = red[p][k][col];
                v0 += t.x; v1 += t.y; v2 += t.z; v3 += t.w;
            }
            *(float4*)(pp + (size_t)k * CH_ * D_) = make_float4(v0, v1, v2, v3);
        }
    }
}

// One block per (b,k): reduce chunks, subtract asum*cluster, L2-normalize row.
__global__ __launch_bounds__(256) void vlad_final(
    const float* __restrict__ part, const float* __restrict__ asum_part,
    const float* __restrict__ cluster, float* __restrict__ out)
{
    const int b = blockIdx.x / K_;
    const int k = blockIdx.x % K_;
    const int tid = threadIdx.x;
    const int d = tid * 2;

    // all 16 chunk loads up-front — deep vmcnt pipeline
    const float* base = part + ((size_t)(b * K_ + k) * CH_) * D_ + d;
    float2 v[CH_];
    #pragma unroll
    for (int c = 0; c < CH_; c++)
        v[c] = *(const float2*)(base + (size_t)c * D_);

    float asv = 0.f;
    #pragma unroll
    for (int c = 0; c < CH_; c++) asv += asum_part[(b * CH_ + c) * K_ + k];

    float s0 = 0.f, s1 = 0.f;
    #pragma unroll
    for (int c = 0; c < CH_; c++) { s0 += v[c].x; s1 += v[c].y; }

    const float2 cv = *(const float2*)(cluster + (size_t)k * D_ + d);
    const float r0 = s0 - asv * cv.x;
    const float r1 = s1 - asv * cv.y;

    float sq = r0 * r0 + r1 * r1;
    #pragma unroll
    for (int off = 32; off > 0; off >>= 1) sq += __shfl_down(sq, off, 64);
    __shared__ float wsum[4];
    if ((tid & 63) == 0) wsum[tid >> 6] = sq;
    __syncthreads();
    const float tot = wsum[0] + wsum[1] + wsum[2] + wsum[3];
    const float scale = rsqrtf(fmaxf(tot, 1e-12f));

    *(float2*)(out + (size_t)(b * K_ + k) * D_ + d) =
        make_float2(r0 * scale, r1 * scale);
}

extern "C" void kernel_launch(void* const* d_in, const int* in_sizes, int n_in,
                              void* d_out, int out_size, void* d_ws, size_t ws_size,
                              hipStream_t stream) {
    const float* feat    = (const float*)d_in[0];
    const float* score   = (const float*)d_in[1];
    const float* cluster = (const float*)d_in[2];
    float* out = (float*)d_out;

    float* part      = (float*)d_ws;                       // B*K*CH*D fp32
    float* asum_part = part + (size_t)B_ * K_ * CH_ * D_;  // B*CH*K fp32

    vlad_accum<<<B_ * CH_, NT1, 0, stream>>>(feat, score, part, asum_part);
    vlad_final<<<B_ * K_, 256, 0, stream>>>(part, asum_part, cluster, out);
}